// Round 1
// baseline (213.715 us; speedup 1.0000x reference)
//
#include <hip/hip_runtime.h>
#include <math.h>

#define NROW 64
#define DIM  131072

// ---------------- complex helpers ----------------
struct cf { float x, y; };
__device__ __forceinline__ cf cadd(cf a, cf b){ return {a.x+b.x, a.y+b.y}; }
__device__ __forceinline__ cf csub(cf a, cf b){ return {a.x-b.x, a.y-b.y}; }
__device__ __forceinline__ cf cmul(cf a, cf b){ return {a.x*b.x - a.y*b.y, a.x*b.y + a.y*b.x}; }
template<int SG> __device__ __forceinline__ cf muli(cf a){
  return (SG > 0) ? cf{-a.y, a.x} : cf{a.y, -a.x};
}
__device__ __forceinline__ float sigmoidf(float x){ return 1.0f/(1.0f + __expf(-x)); }

// DFT with exponent sign SG: X[k] = sum_n x[n] * e^{SG*2*pi*i*n*k/N}  (SG=-1 forward)
template<int SG> __device__ __forceinline__ void fft4(cf&a0, cf&a1, cf&a2, cf&a3){
  cf e0=cadd(a0,a2), e1=csub(a0,a2), o0=cadd(a1,a3), o1=csub(a1,a3);
  cf w=muli<SG>(o1);
  a0=cadd(e0,o0); a2=csub(e0,o0); a1=cadd(e1,w); a3=csub(e1,w);
}

template<int SG> __device__ __forceinline__ void fft8(cf v[8]){
  cf e0=v[0], e1=v[2], e2=v[4], e3=v[6];
  cf o0=v[1], o1=v[3], o2=v[5], o3=v[7];
  fft4<SG>(e0,e1,e2,e3); fft4<SG>(o0,o1,o2,o3);
  const float R=0.70710678118654752f;
  cf w1=cmul(o1, cf{R, (float)SG*R});
  cf w2=muli<SG>(o2);
  cf w3=cmul(o3, cf{-R, (float)SG*R});
  v[0]=cadd(e0,o0); v[4]=csub(e0,o0);
  v[1]=cadd(e1,w1); v[5]=csub(e1,w1);
  v[2]=cadd(e2,w2); v[6]=csub(e2,w2);
  v[3]=cadd(e3,w3); v[7]=csub(e3,w3);
}

template<int SG> __device__ __forceinline__ void fft16(cf v[16]){
  cf e[8], o[8];
  #pragma unroll
  for(int i=0;i<8;i++){ e[i]=v[2*i]; o[i]=v[2*i+1]; }
  fft8<SG>(e); fft8<SG>(o);
  const float C[8]={1.f,0.92387953251128674f,0.70710678118654752f,0.38268343236508977f,
                    0.f,-0.38268343236508977f,-0.70710678118654752f,-0.92387953251128674f};
  const float S[8]={0.f,0.38268343236508977f,0.70710678118654752f,0.92387953251128674f,
                    1.f,0.92387953251128674f,0.70710678118654752f,0.38268343236508977f};
  #pragma unroll
  for(int k=0;k<8;k++){
    cf w=cmul(o[k], cf{C[k], (float)SG*S[k]});
    v[k]=cadd(e[k],w); v[k+8]=csub(e[k],w);
  }
}

// ---------------- K0: dummy_ptr + scalar tail ----------------
__global__ void k0_tail(float* __restrict__ dout, int cplx){
  int t = threadIdx.x;
  size_t base = (size_t)2*NROW*DIM*cplx;
  if(t < NROW) dout[base + t] = 0.f;
  else if(t == NROW) dout[base + NROW] = 1.0f;
}

// ---------------- K1: global max|z| ----------------
__global__ __launch_bounds__(256) void k1_maxabs(const float* __restrict__ z, unsigned* __restrict__ dst){
  __shared__ float red[256];
  size_t i0 = (size_t)blockIdx.x*blockDim.x + threadIdx.x;
  size_t stride = (size_t)gridDim.x*blockDim.x;
  const float4* z4 = (const float4*)z;
  size_t n4 = (size_t)NROW*DIM/4;
  float m = 0.f;
  for(size_t i=i0;i<n4;i+=stride){
    float4 v=z4[i];
    m = fmaxf(m, fmaxf(fmaxf(fabsf(v.x),fabsf(v.y)), fmaxf(fabsf(v.z),fabsf(v.w))));
  }
  red[threadIdx.x]=m; __syncthreads();
  #pragma unroll
  for(int s=128;s>0;s>>=1){
    if(threadIdx.x<(unsigned)s) red[threadIdx.x]=fmaxf(red[threadIdx.x],red[threadIdx.x+s]);
    __syncthreads();
  }
  if(threadIdx.x==0) atomicMax(dst, __float_as_uint(red[0]));
}

// ---------------- K2: forward stage-1 (FFT-256 over n2) + new_trace ----------------
// n = n2*512 + n1. For fixed n1: B[k2][n1] = W_N^{n1*k2} * sum_{n2} c[n2*512+n1] W_256^{n2*k2}
// c = z + i*trace (unnormalized z; scale applied in K3).
__global__ __launch_bounds__(256) void k2_fwd1(
    const float* __restrict__ z, const float* __restrict__ tr,
    const float* __restrict__ ctrl, const unsigned* __restrict__ maxbits,
    float2* __restrict__ Bws, float* __restrict__ out_nt, int cplx)
{
  __shared__ float reb[4384], imb[4384];
  __shared__ float twc[256], tws[256];
  int t = threadIdx.x;
  int b = blockIdx.x >> 5;
  int n1b = (blockIdx.x & 31) << 4;
  {
    float sv, cv;
    __sincosf(-0.0245436926061703f * (float)t, &sv, &cv); // -2*pi/256 * t
    twc[t]=cv; tws[t]=sv;
  }
  float s = 1.0f/(__uint_as_float(*maxbits) + 1e-6f);
  float gs = sigmoidf(ctrl[b*3+0]);
  const float* zr  = z  + (size_t)b*DIM;
  const float* trr = tr + (size_t)b*DIM;
  #pragma unroll
  for(int it=0; it<16; ++it){
    int e = t + 256*it;
    int n2 = e >> 4, i = e & 15;
    int n = n2*512 + n1b + i;
    float zv = zr[n], tv = trr[n];
    reb[n2*17+i] = zv; imb[n2*17+i] = tv;
    float nt = fmaf(gs*s, zv, tv);        // new_trace = trace + store*s*z (exact)
    size_t oidx = (size_t)b*DIM + n;
    if(cplx == 2) ((float2*)out_nt)[oidx] = make_float2(nt, 0.f);
    else out_nt[oidx] = nt;
  }
  __syncthreads();
  int f = t & 15, p = t >> 4;
  cf v[16];
  #pragma unroll
  for(int q=0;q<16;q++){ int n2=q*16+p; v[q].x=reb[n2*17+f]; v[q].y=imb[n2*17+f]; }
  fft16<-1>(v);
  #pragma unroll
  for(int kq=1;kq<16;kq++){ int tt=(p*kq)&255; v[kq]=cmul(v[kq], cf{twc[tt], tws[tt]}); }
  __syncthreads();
  #pragma unroll
  for(int kq=0;kq<16;kq++){ reb[f*274 + kq*17 + p]=v[kq].x; imb[f*274 + kq*17 + p]=v[kq].y; }
  __syncthreads();
  #pragma unroll
  for(int pp=0;pp<16;pp++){ v[pp].x=reb[f*274 + p*17 + pp]; v[pp].y=imb[f*274 + p*17 + pp]; }
  fft16<-1>(v);
  int nn1 = n1b + f;
  #pragma unroll
  for(int kp=0;kp<16;kp++){
    int k2 = kp*16 + p;
    int tt = (nn1*k2) & (DIM-1);
    float tf = (float)(tt - ((tt >= (DIM/2)) ? DIM : 0));
    float sv, cv;
    __sincosf(-4.793689960382698e-05f * tf, &sv, &cv);  // -2*pi/131072
    cf r = cmul(v[kp], cf{cv, sv});
    Bws[((size_t)b<<17) + (size_t)k2*512 + nn1] = make_float2(r.x, r.y);
  }
}

// ---------------- K3: FFT-512 columns, Hermitian split + product, IFFT-512 ----------------
// 3x radix-8 register FFT; buffers X->T->X->T per call; result lands in T.
template<int SG>
__device__ __forceinline__ void fft512_block(
    float* Xre, float* Xim, float* Tre, float* Tim,
    int lane, const float* twc, const float* tws)
{
  cf v[8];
  #pragma unroll
  for(int q=0;q<8;q++){ v[q].x=Xre[q*64+lane]; v[q].y=Xim[q*64+lane]; }
  fft8<SG>(v);
  #pragma unroll
  for(int kq=1;kq<8;kq++){ int tt=(lane*kq)&511; v[kq]=cmul(v[kq], cf{twc[tt], (float)SG*tws[tt]}); }
  #pragma unroll
  for(int kq=0;kq<8;kq++){ Tre[lane*9+kq]=v[kq].x; Tim[lane*9+kq]=v[kq].y; }
  __syncthreads();
  int kQ = lane>>3, pp = lane&7;
  #pragma unroll
  for(int q=0;q<8;q++){ int idx=(q*8+pp)*9+kQ; v[q].x=Tre[idx]; v[q].y=Tim[idx]; }
  fft8<SG>(v);
  #pragma unroll
  for(int kq=1;kq<8;kq++){ int tt=(pp*kq*8)&511; v[kq]=cmul(v[kq], cf{twc[tt], (float)SG*tws[tt]}); }
  __syncthreads();   // all T reads done before X overwritten? (X reads were in phase A, T reads just above)
  #pragma unroll
  for(int kq=0;kq<8;kq++){ Xre[pp*73+kq*9+kQ]=v[kq].x; Xim[pp*73+kq*9+kQ]=v[kq].y; }
  __syncthreads();
  #pragma unroll
  for(int p2=0;p2<8;p2++){ int idx=p2*73 + kQ*9 + pp; v[p2].x=Xre[idx]; v[p2].y=Xim[idx]; }
  fft8<SG>(v);
  #pragma unroll
  for(int kp=0;kp<8;kp++){ int k=kp*64 + kQ*8 + pp; Tre[k]=v[kp].x; Tim[k]=v[kp].y; }
  // caller must __syncthreads() before consuming T
}

__global__ __launch_bounds__(128) void k3_mid(
    float2* __restrict__ Bws, const float* __restrict__ ctrl,
    const unsigned* __restrict__ maxbits)
{
  __shared__ float Xs[4*584], Ts[4*584];
  __shared__ float twc[512], tws[512];
  int t = threadIdx.x;
  int b  = blockIdx.x >> 7;
  int pr = blockIdx.x & 127;
  int cA = (pr==0) ? 0   : pr;
  int cB = (pr==0) ? 128 : 256-pr;
  int col = t >> 6, lane = t & 63;
  int myc = col ? cB : cA;
  for(int i=t;i<512;i+=128){
    float sv,cv; __sincosf(0.0122718463030851f*(float)i, &sv, &cv); // +2*pi/512
    twc[i]=cv; tws[i]=sv;
  }
  float s = 1.0f/(__uint_as_float(*maxbits)+1e-6f);
  float gs = sigmoidf(ctrl[b*3+0]);
  float alpha = sigmoidf(ctrl[b*3+1]) * (1.0f/(float)DIM);
  float* Xre = Xs + (2*col)*584; float* Xim = Xre + 584;
  float* Tre = Ts + (2*col)*584; float* Tim = Tre + 584;
  float2* colp = Bws + ((size_t)b<<17) + ((size_t)myc<<9);
  #pragma unroll
  for(int r=0;r<8;r++){ float2 vv = colp[lane + 64*r]; Xre[lane+64*r]=vv.x; Xim[lane+64*r]=vv.y; }
  __syncthreads();
  fft512_block<-1>(Xre, Xim, Tre, Tim, lane, twc, tws);
  __syncthreads();
  // Hermitian split + pointwise product; P into X
  const float* Pre = (pr==0) ? Tre : (Ts + (2*(1-col))*584);
  const float* Pim = Pre + 584;
  #pragma unroll
  for(int r=0;r<8;r++){
    int k1  = lane + 64*r;
    int k1p = (myc==0) ? ((512-k1)&511) : (511-k1);
    float cr = Tre[k1], ci = Tim[k1];
    float qr = Pre[k1p], qi = -Pim[k1p];          // conj(C[N-k])
    float zur = 0.5f*(cr+qr), zui = 0.5f*(ci+qi); // Z_unnorm
    float dr = cr-qr, di = ci-qi;
    float tfr = 0.5f*di, tfi = -0.5f*dr;          // trace_f
    float szr = s*zur, szi = s*zui;               // z_f (normalized)
    float ntr = fmaf(gs, szr, tfr), nti = fmaf(gs, szi, tfi);
    float prr = (ntr*szr + nti*szi)*alpha;        // NT * conj(sZ) * retrieve/N
    float pii = (nti*szr - ntr*szi)*alpha;
    Xre[k1]=prr; Xim[k1]=pii;
  }
  __syncthreads();
  fft512_block<1>(Xre, Xim, Tre, Tim, lane, twc, tws);
  __syncthreads();
  #pragma unroll
  for(int r=0;r<8;r++){
    int m1 = lane + 64*r;
    int tt = (m1*myc) & (DIM-1);
    float tf = (float)(tt - ((tt>=(DIM/2))?DIM:0));
    float sv,cv; __sincosf(4.793689960382698e-05f*tf, &sv, &cv); // +2*pi/131072
    cf r2 = cmul(cf{Tre[m1],Tim[m1]}, cf{cv,sv});
    colp[m1] = make_float2(r2.x, r2.y);
  }
}

// ---------------- K4: inverse stage-2 (IFFT-256 over k2), write `read` ----------------
__global__ __launch_bounds__(256) void k4_inv2(
    const float2* __restrict__ Qws, float* __restrict__ dout, int cplx)
{
  __shared__ float reb[4384], imb[4384];
  __shared__ float twc[256], tws[256];
  int t = threadIdx.x;
  int b = blockIdx.x >> 5;
  int m1b = (blockIdx.x & 31) << 4;
  {
    float sv, cv;
    __sincosf(0.0245436926061703f * (float)t, &sv, &cv); // +2*pi/256 * t
    twc[t]=cv; tws[t]=sv;
  }
  #pragma unroll
  for(int it=0; it<16; ++it){
    int e = t + 256*it;
    int k2 = e >> 4, i = e & 15;
    float2 q = Qws[((size_t)b<<17) + (size_t)k2*512 + m1b + i];
    reb[k2*17+i]=q.x; imb[k2*17+i]=q.y;
  }
  __syncthreads();
  int f = t & 15, p = t >> 4;
  cf v[16];
  #pragma unroll
  for(int q=0;q<16;q++){ int k2=q*16+p; v[q].x=reb[k2*17+f]; v[q].y=imb[k2*17+f]; }
  fft16<1>(v);
  #pragma unroll
  for(int kq=1;kq<16;kq++){ int tt=(p*kq)&255; v[kq]=cmul(v[kq], cf{twc[tt], tws[tt]}); }
  __syncthreads();
  #pragma unroll
  for(int kq=0;kq<16;kq++){ reb[f*274+kq*17+p]=v[kq].x; imb[f*274+kq*17+p]=v[kq].y; }
  __syncthreads();
  #pragma unroll
  for(int pp=0;pp<16;pp++){ v[pp].x=reb[f*274+p*17+pp]; v[pp].y=imb[f*274+p*17+pp]; }
  fft16<1>(v);
  #pragma unroll
  for(int kp=0;kp<16;kp++){
    int m2 = kp*16 + p;
    size_t n = (size_t)(m1b + f) + (size_t)512*m2;
    size_t oidx = (size_t)b*DIM + n;
    if(cplx==2) ((float2*)dout)[oidx] = make_float2(v[kp].x, 0.f);
    else dout[oidx] = v[kp].x;
  }
}

// ---------------- launch ----------------
extern "C" void kernel_launch(void* const* d_in, const int* in_sizes, int n_in,
                              void* d_out, int out_size, void* d_ws, size_t ws_size,
                              hipStream_t stream)
{
  (void)in_sizes; (void)n_in; (void)ws_size;
  const float* z    = (const float*)d_in[0];
  const float* tr   = (const float*)d_in[1];
  const float* ctrl = (const float*)d_in[2];
  float* dout = (float*)d_out;
  // complex64 outputs flattened as interleaved float32 -> out_size = 2*2*B*DIM + B + 1.
  // Fallback: real-only layout if out_size is small.
  int cplx = (out_size > 20000000) ? 2 : 1;
  unsigned* maxbits = (unsigned*)d_ws;
  float2* Bws = (float2*)((char*)d_ws + 256);   // 64 MiB intermediate, in-place through K3

  hipMemsetAsync(d_ws, 0, 4, stream);
  hipLaunchKernelGGL(k0_tail,  dim3(1),    dim3(128), 0, stream, dout, cplx);
  hipLaunchKernelGGL(k1_maxabs,dim3(256),  dim3(256), 0, stream, z, maxbits);
  hipLaunchKernelGGL(k2_fwd1,  dim3(2048), dim3(256), 0, stream,
                     z, tr, ctrl, maxbits, Bws, dout + (size_t)NROW*DIM*cplx, cplx);
  hipLaunchKernelGGL(k3_mid,   dim3(8192), dim3(128), 0, stream, Bws, ctrl, maxbits);
  hipLaunchKernelGGL(k4_inv2,  dim3(2048), dim3(256), 0, stream, Bws, dout, cplx);
}